// Round 2
// baseline (431.111 us; speedup 1.0000x reference)
//
#include <hip/hip_runtime.h>

// Problem: B=32, C_IN=C_OUT=64, H=W=128, PODS=2.
// Pipeline: f2 = FWHT2D(x); f6 = sum_i soft_thresh(v_i * (W_i @ f2), T_i);
//           out = FWHT2D(f6)/16384 + x.
// All intermediates live in d_out (in-place); d_ws holds only transposed weights (32 KB).

#define SWZ(r, j) ((j) ^ ((r) & 31))   // float4-granularity XOR swizzle per row

__device__ __forceinline__ void fwht128(float* d) {
  #pragma unroll
  for (int st = 0; st < 7; ++st) {
    const int h = 1 << st;
    #pragma unroll
    for (int k = 0; k < 64; ++k) {
      const int pos = ((k >> st) << (st + 1)) | (k & (h - 1));
      const float a = d[pos], b = d[pos + h];
      d[pos]     = a + b;
      d[pos + h] = a - b;
    }
  }
}

// ---- kernel A: forward 2D FWHT per (b,c) plane: x -> out ----
__global__ __launch_bounds__(128) void fwht2d_fwd_kernel(const float* __restrict__ in,
                                                         float* __restrict__ out) {
  __shared__ float4 s[4096];                       // 64 KB: 128 rows x 32 float4
  const size_t plane = blockIdx.x;
  const float4* src = (const float4*)in + plane * 4096;
  float4* dst = (float4*)out + plane * 4096;
  const int t = threadIdx.x;

  #pragma unroll
  for (int i = 0; i < 32; ++i) {
    const int idx = t + i * 128;
    const int r = idx >> 5, j = idx & 31;
    s[r * 32 + SWZ(r, j)] = src[idx];
  }
  __syncthreads();

  float d[128];
  { // H axis: thread t owns column w=t (b32 reads, conflict-free)
    const int j = t >> 2, e = t & 3;
    #pragma unroll
    for (int h = 0; h < 128; ++h)
      d[h] = ((const float*)&s[h * 32 + SWZ(h, j)])[e];
    fwht128(d);
    #pragma unroll
    for (int h = 0; h < 128; ++h)
      ((float*)&s[h * 32 + SWZ(h, j)])[e] = d[h];
  }
  __syncthreads();
  { // W axis: thread t owns row r=t (b128 reads, swizzled -> at LDS floor)
    #pragma unroll
    for (int j = 0; j < 32; ++j) {
      const float4 q = s[t * 32 + SWZ(t, j)];
      d[4*j] = q.x; d[4*j+1] = q.y; d[4*j+2] = q.z; d[4*j+3] = q.w;
    }
    fwht128(d);
    #pragma unroll
    for (int j = 0; j < 32; ++j) {
      float4 q; q.x = d[4*j]; q.y = d[4*j+1]; q.z = d[4*j+2]; q.w = d[4*j+3];
      s[t * 32 + SWZ(t, j)] = q;
    }
  }
  __syncthreads();
  #pragma unroll
  for (int i = 0; i < 32; ++i) {
    const int idx = t + i * 128;
    const int r = idx >> 5, j = idx & 31;
    dst[idx] = s[r * 32 + SWZ(r, j)];
  }
}

// ---- kernel C: inverse 2D FWHT per (b,o) plane, scale 1/16384, + x ----
__global__ __launch_bounds__(128) void fwht2d_inv_add_kernel(float* __restrict__ io,
                                                             const float* __restrict__ x) {
  __shared__ float4 s[4096];
  const size_t plane = blockIdx.x;
  float4* dst = (float4*)io + plane * 4096;
  const float4* xsrc = (const float4*)x + plane * 4096;
  const int t = threadIdx.x;

  #pragma unroll
  for (int i = 0; i < 32; ++i) {
    const int idx = t + i * 128;
    const int r = idx >> 5, j = idx & 31;
    s[r * 32 + SWZ(r, j)] = dst[idx];
  }
  __syncthreads();

  float d[128];
  {
    const int j = t >> 2, e = t & 3;
    #pragma unroll
    for (int h = 0; h < 128; ++h)
      d[h] = ((const float*)&s[h * 32 + SWZ(h, j)])[e];
    fwht128(d);
    #pragma unroll
    for (int h = 0; h < 128; ++h)
      ((float*)&s[h * 32 + SWZ(h, j)])[e] = d[h];
  }
  __syncthreads();
  {
    #pragma unroll
    for (int j = 0; j < 32; ++j) {
      const float4 q = s[t * 32 + SWZ(t, j)];
      d[4*j] = q.x; d[4*j+1] = q.y; d[4*j+2] = q.z; d[4*j+3] = q.w;
    }
    fwht128(d);
    #pragma unroll
    for (int j = 0; j < 32; ++j) {
      float4 q; q.x = d[4*j]; q.y = d[4*j+1]; q.z = d[4*j+2]; q.w = d[4*j+3];
      s[t * 32 + SWZ(t, j)] = q;
    }
  }
  __syncthreads();
  const float sc = 1.0f / 16384.0f;
  #pragma unroll
  for (int i = 0; i < 32; ++i) {
    const int idx = t + i * 128;
    const int r = idx >> 5, j = idx & 31;
    const float4 q = s[r * 32 + SWZ(r, j)];
    const float4 xv = xsrc[idx];
    float4 o;
    o.x = q.x * sc + xv.x;
    o.y = q.y * sc + xv.y;
    o.z = q.z * sc + xv.z;
    o.w = q.w * sc + xv.w;
    dst[idx] = o;
  }
}

// ---- weight transpose: conv_w[p][o][c] -> wt[p][c][o] (into ws) ----
__global__ __launch_bounds__(256) void wtr_kernel(const float* __restrict__ w,
                                                  float* __restrict__ wt) {
  const int i = blockIdx.x * 256 + threadIdx.x;   // 0..8191
  const int p = i >> 12, o = (i >> 6) & 63, c = i & 63;
  wt[p * 4096 + c * 64 + o] = w[i];
}

// ---- kernel B: per-pod channel mix + soft-threshold, in-place on io ----
// block: 256 threads; tile = (all 64 ch) x 128 spatial locs within one b.
__global__ __launch_bounds__(256) void mix_kernel(float* __restrict__ io,
                                                  const float* __restrict__ v,
                                                  const float* __restrict__ T,
                                                  const float* __restrict__ wt) {
  __shared__ float sa[64 * 128];    // 32 KB: f2 tile [c][loc]
  __shared__ float sw[2 * 64 * 64]; // 32 KB: wt [p][c][o]
  const int t = threadIdx.x;
  const int b = blockIdx.x >> 7;
  const int hw0 = (blockIdx.x & 127) << 7;
  float* base = io + ((size_t)b << 20);           // b * 64 * 16384

  #pragma unroll
  for (int i = 0; i < 32; ++i)
    sw[t + i * 256] = wt[t + i * 256];
  #pragma unroll
  for (int i = 0; i < 8; ++i) {
    const int j = t + i * 256;                    // float4 index 0..2047
    const int c = j >> 5, col4 = j & 31;
    *(float4*)&sa[c * 128 + col4 * 4] =
        *(const float4*)(base + (size_t)c * 16384 + hw0 + col4 * 4);
  }
  __syncthreads();

  const int tx = t & 15;            // 8 locs: loc0..loc0+7
  const int ty = t >> 4;            // 4 outputs: o = ty*4..ty*4+3
  const int loc0 = tx * 8;

  float facc[4][8];
  #pragma unroll
  for (int k = 0; k < 4; ++k)
    #pragma unroll
    for (int j = 0; j < 8; ++j) facc[k][j] = 0.f;

  #pragma unroll
  for (int p = 0; p < 2; ++p) {
    float acc[4][8];
    #pragma unroll
    for (int k = 0; k < 4; ++k)
      #pragma unroll
      for (int j = 0; j < 8; ++j) acc[k][j] = 0.f;

    #pragma unroll 4
    for (int c = 0; c < 64; ++c) {
      const float4 w4 = *(const float4*)&sw[p * 4096 + c * 64 + ty * 4];
      const float4 a0 = *(const float4*)&sa[c * 128 + loc0];
      const float4 a1 = *(const float4*)&sa[c * 128 + loc0 + 4];
      const float wv[4] = {w4.x, w4.y, w4.z, w4.w};
      const float av[8] = {a0.x, a0.y, a0.z, a0.w, a1.x, a1.y, a1.z, a1.w};
      #pragma unroll
      for (int k = 0; k < 4; ++k)
        #pragma unroll
        for (int j = 0; j < 8; ++j)
          acc[k][j] = fmaf(wv[k], av[j], acc[k][j]);
    }

    const float4 v0 = *(const float4*)(v + p * 16384 + hw0 + loc0);
    const float4 v1 = *(const float4*)(v + p * 16384 + hw0 + loc0 + 4);
    const float4 T0 = *(const float4*)(T + p * 16384 + hw0 + loc0);
    const float4 T1 = *(const float4*)(T + p * 16384 + hw0 + loc0 + 4);
    const float vv[8] = {v0.x, v0.y, v0.z, v0.w, v1.x, v1.y, v1.z, v1.w};
    const float tv[8] = {T0.x, T0.y, T0.z, T0.w, T1.x, T1.y, T1.z, T1.w};
    #pragma unroll
    for (int k = 0; k < 4; ++k)
      #pragma unroll
      for (int j = 0; j < 8; ++j) {
        const float fv = acc[k][j] * vv[j];       // v * (W @ f2) == W @ (v*f2)
        const float m = fabsf(fv) - tv[j];        // T >= 0 so relu(T)=T
        facc[k][j] += (m > 0.f) ? copysignf(m, fv) : 0.f;
      }
  }

  #pragma unroll
  for (int k = 0; k < 4; ++k) {
    const int o = ty * 4 + k;
    float* orow = base + (size_t)o * 16384 + hw0 + loc0;
    float4 q0 = {facc[k][0], facc[k][1], facc[k][2], facc[k][3]};
    float4 q1 = {facc[k][4], facc[k][5], facc[k][6], facc[k][7]};
    *(float4*)orow = q0;
    *(float4*)(orow + 4) = q1;
  }
}

extern "C" void kernel_launch(void* const* d_in, const int* in_sizes, int n_in,
                              void* d_out, int out_size, void* d_ws, size_t ws_size,
                              hipStream_t stream) {
  const float* x = (const float*)d_in[0];
  const float* v = (const float*)d_in[1];
  const float* T = (const float*)d_in[2];
  const float* w = (const float*)d_in[3];
  float* out = (float*)d_out;
  float* wt = (float*)d_ws;                       // 8192 floats = 32 KB

  wtr_kernel<<<32, 256, 0, stream>>>(w, wt);
  fwht2d_fwd_kernel<<<2048, 128, 0, stream>>>(x, out);      // x -> f2 (in d_out)
  mix_kernel<<<4096, 256, 0, stream>>>(out, v, T, wt);      // f2 -> f6 (in place)
  fwht2d_inv_add_kernel<<<2048, 128, 0, stream>>>(out, x);  // f6 -> out (in place)
}

// Round 8
// 319.323 us; speedup vs baseline: 1.3501x; 1.3501x over previous
//
#include <hip/hip_runtime.h>

// B=32, C_IN=C_OUT=64, H=W=128, PODS=2.
// f2 = FWHT2D(x); f6 = sum_p soft_thresh(v_p * (W_p @ f2), T_p); out = FWHT2D(f6)/16384 + x.
// Identity used: W @ (v*f2) == v * (W @ f2)  (v is scalar per (h,w)).
//
// Path A (ws_size >= 134.3 MB): f2,f6 stored bf16 in d_ws; mix uses bf16 MFMA. ~670 MB traffic.
// Path B (fallback): f2,f6 fp32 in d_out (in-place per-tile safe: each mix block reads and
// writes only its own disjoint hw-column range); mix params deliberately NOT __restrict__
// because f2 and f6 alias in this path.

typedef short short8 __attribute__((ext_vector_type(8)));
typedef float f32x4 __attribute__((ext_vector_type(4)));

#define SWZ_COL(r, j) ((j) ^ ((r) & 31))   // float4-granularity XOR swizzle per row

__device__ __forceinline__ unsigned short f2bf(float f) {
  unsigned int u = __float_as_uint(f);
  u = (u + 0x7FFFu + ((u >> 16) & 1u)) >> 16;   // RNE
  return (unsigned short)u;
}
__device__ __forceinline__ float bf2f(unsigned short h) {
  return __uint_as_float(((unsigned int)h) << 16);
}

__device__ __forceinline__ void fwht32(float* d) {
  #pragma unroll
  for (int st = 0; st < 5; ++st) {
    const int h = 1 << st;
    #pragma unroll
    for (int k = 0; k < 16; ++k) {
      const int pos = ((k >> st) << (st + 1)) | (k & (h - 1));
      const float a = d[pos], b = d[pos + h];
      d[pos] = a + b;
      d[pos + h] = a - b;
    }
  }
}

// ---------------- 2D FWHT core (shared by fwd/inv) ------------------
// s: 128x32 float4, col-swizzled. 512 threads. Does full 128x128 2D FWHT.
// Strides 1..16 in registers; strides 32,64 of the h-axis folded into the
// row-pass reads; strides 32,64 of the w-axis folded into the caller's store.
__device__ __forceinline__ void fwht2d_core(float4* s, int t) {
  float d[32];
  { // col pass: transform along h. thread: w = t&127, q = t>>7 -> rows [32q,32q+32)
    const int w = t & 127, q = t >> 7;
    const int j4 = w >> 2, e = w & 3;
    #pragma unroll
    for (int k = 0; k < 32; ++k) {
      const int r = 32 * q + k;
      d[k] = ((const float*)&s[r * 32 + SWZ_COL(r, j4)])[e];
    }
    fwht32(d);
    __syncthreads();   // ensure all reads done before writes (same cells)
    #pragma unroll
    for (int k = 0; k < 32; ++k) {
      const int r = 32 * q + k;
      ((float*)&s[r * 32 + SWZ_COL(r, j4)])[e] = d[k];
    }
  }
  __syncthreads();
  { // row pass: r = t&127, q = t>>7 -> w in [32q,32q+32); fold h-strides 32,64 on read
    const int r = t & 127, q = t >> 7;
    const int rl = r & 31, a = r >> 5;
    const float sA = (a & 1) ? -1.f : 1.f;
    const float sB = (a & 2) ? -1.f : 1.f;
    #pragma unroll
    for (int j4 = 0; j4 < 8; ++j4) {
      const int col4 = q * 8 + j4;
      const int sc = col4 ^ rl;    // same swizzled col for rl, rl+32, rl+64, rl+96
      const float4 c0 = s[(rl)      * 32 + sc];
      const float4 c1 = s[(rl + 32) * 32 + sc];
      const float4 c2 = s[(rl + 64) * 32 + sc];
      const float4 c3 = s[(rl + 96) * 32 + sc];
      d[4*j4+0] = c0.x + sA*c1.x + sB*c2.x + sA*sB*c3.x;
      d[4*j4+1] = c0.y + sA*c1.y + sB*c2.y + sA*sB*c3.y;
      d[4*j4+2] = c0.z + sA*c1.z + sB*c2.z + sA*sB*c3.z;
      d[4*j4+3] = c0.w + sA*c1.w + sB*c2.w + sA*sB*c3.w;
    }
    fwht32(d);
    __syncthreads();
    #pragma unroll
    for (int j4 = 0; j4 < 8; ++j4) {
      const int col4 = q * 8 + j4;
      float4 qv = {d[4*j4], d[4*j4+1], d[4*j4+2], d[4*j4+3]};
      s[r * 32 + SWZ_COL(r, col4)] = qv;
    }
  }
  __syncthreads();
  // remaining w-strides 32,64 are combined by the caller at store time.
}

// combine the pending w-strides 32,64 for float4 at (h, col4 in a-block a)
__device__ __forceinline__ float4 wcombine(const float4* s, int h, int j4l, int a) {
  const float sA = (a & 1) ? -1.f : 1.f;
  const float sB = (a & 2) ? -1.f : 1.f;
  const float4 c0 = s[h * 32 + SWZ_COL(h, 0  + j4l)];
  const float4 c1 = s[h * 32 + SWZ_COL(h, 8  + j4l)];
  const float4 c2 = s[h * 32 + SWZ_COL(h, 16 + j4l)];
  const float4 c3 = s[h * 32 + SWZ_COL(h, 24 + j4l)];
  float4 F;
  F.x = c0.x + sA*c1.x + sB*c2.x + sA*sB*c3.x;
  F.y = c0.y + sA*c1.y + sB*c2.y + sA*sB*c3.y;
  F.z = c0.z + sA*c1.z + sB*c2.z + sA*sB*c3.z;
  F.w = c0.w + sA*c1.w + sB*c2.w + sA*sB*c3.w;
  return F;
}

// ---- forward 2D FWHT: x(f32) -> f2 (bf16 or f32) ----
template <bool BF16OUT>
__global__ __launch_bounds__(512) void fwht2d_fwd_kernel(const float* __restrict__ in,
                                                         void* __restrict__ out) {
  __shared__ float4 s[4096];
  const size_t plane = blockIdx.x;
  const int t = threadIdx.x;
  const float4* src = (const float4*)in + plane * 4096;

  #pragma unroll
  for (int i = 0; i < 8; ++i) {
    const int idx = i * 512 + t;
    const int r = idx >> 5, j = idx & 31;
    s[r * 32 + SWZ_COL(r, j)] = src[idx];
  }
  __syncthreads();

  fwht2d_core(s, t);

  if (BF16OUT) {
    unsigned short* dst = (unsigned short*)out + plane * 16384;
    #pragma unroll
    for (int ss = 0; ss < 4; ++ss) {
      const int base = ss * 4096 + t * 8;
      const int h = base >> 7, w0 = base & 127;
      const int a = w0 >> 5, j4l = (w0 & 31) >> 2;
      const float4 F0 = wcombine(s, h, j4l, a);
      const float4 F1 = wcombine(s, h, j4l + 1, a);
      union { unsigned short u[8]; uint4 q; } pk;
      pk.u[0]=f2bf(F0.x); pk.u[1]=f2bf(F0.y); pk.u[2]=f2bf(F0.z); pk.u[3]=f2bf(F0.w);
      pk.u[4]=f2bf(F1.x); pk.u[5]=f2bf(F1.y); pk.u[6]=f2bf(F1.z); pk.u[7]=f2bf(F1.w);
      *(uint4*)(dst + base) = pk.q;
    }
  } else {
    float4* dst = (float4*)out + plane * 4096;
    #pragma unroll
    for (int ss = 0; ss < 8; ++ss) {
      const int base = ss * 2048 + t * 4;
      const int h = base >> 7, w0 = base & 127;
      const int a = w0 >> 5, j4l = (w0 & 31) >> 2;
      dst[base >> 2] = wcombine(s, h, j4l, a);
    }
  }
}

// ---- inverse 2D FWHT (+scale, +x): f6 (bf16 or f32) -> out f32 ----
template <bool BF16IN>
__global__ __launch_bounds__(512) void fwht2d_inv_kernel(const void* __restrict__ f6,
                                                         const float* __restrict__ x,
                                                         float* __restrict__ out) {
  __shared__ float4 s[4096];
  const size_t plane = blockIdx.x;
  const int t = threadIdx.x;

  if (BF16IN) {
    const unsigned short* src = (const unsigned short*)f6 + plane * 16384;
    #pragma unroll
    for (int ss = 0; ss < 4; ++ss) {
      const int base = ss * 4096 + t * 8;
      union { unsigned short u[8]; uint4 q; } pk;
      pk.q = *(const uint4*)(src + base);
      const int r = base >> 7, j4 = (base & 127) >> 2;
      float4 f0 = {bf2f(pk.u[0]), bf2f(pk.u[1]), bf2f(pk.u[2]), bf2f(pk.u[3])};
      float4 f1 = {bf2f(pk.u[4]), bf2f(pk.u[5]), bf2f(pk.u[6]), bf2f(pk.u[7])};
      s[r * 32 + SWZ_COL(r, j4)] = f0;
      s[r * 32 + SWZ_COL(r, j4 + 1)] = f1;
    }
  } else {
    const float4* src = (const float4*)f6 + plane * 4096;
    #pragma unroll
    for (int i = 0; i < 8; ++i) {
      const int idx = i * 512 + t;
      const int r = idx >> 5, j = idx & 31;
      s[r * 32 + SWZ_COL(r, j)] = src[idx];
    }
  }
  __syncthreads();

  fwht2d_core(s, t);

  const float sc = 1.0f / 16384.0f;
  const float4* xsrc = (const float4*)x + plane * 4096;
  float4* dst = (float4*)out + plane * 4096;
  #pragma unroll
  for (int ss = 0; ss < 8; ++ss) {
    const int base = ss * 2048 + t * 4;
    const int h = base >> 7, w0 = base & 127;
    const int a = w0 >> 5, j4l = (w0 & 31) >> 2;
    const float4 F = wcombine(s, h, j4l, a);
    const float4 xv = xsrc[base >> 2];
    float4 o;
    o.x = F.x * sc + xv.x; o.y = F.y * sc + xv.y;
    o.z = F.z * sc + xv.z; o.w = F.w * sc + xv.w;
    dst[base >> 2] = o;
  }
}

// ---- weight fragment prep: conv_w[p][o][c] f32 -> MFMA A-fragments bf16 ----
// frag layout: idx = p<<12 | ot<<10 | kc<<9 | lane<<3 | i
// value = W[p][ot*16 + (lane&15)][kc*32 + 8*(lane>>4) + i]
__global__ __launch_bounds__(256) void prep_frags_kernel(const float* __restrict__ w,
                                                         unsigned short* __restrict__ frags) {
  const int tid = blockIdx.x * 256 + threadIdx.x;   // 0..8191
  const int i = tid & 7, lane = (tid >> 3) & 63;
  const int kc = (tid >> 9) & 1, ot = (tid >> 10) & 3, p = (tid >> 12) & 1;
  const int o = ot * 16 + (lane & 15);
  const int c = kc * 32 + 8 * (lane >> 4) + i;
  frags[tid] = f2bf(w[p * 4096 + o * 64 + c]);
}

// ---- mix: per (b, 64-hw tile): f6[o][hw] = sum_p st(v_p * (W_p @ f2), T_p) via bf16 MFMA ----
// NOTE: f2/f6 may alias (path B, in-place) -> no __restrict__ on them.
template <bool IN_BF16, bool OUT_BF16>
__global__ __launch_bounds__(256) void mix_kernel(const void* f2,
                                                  void* f6,
                                                  const float* __restrict__ v,
                                                  const float* __restrict__ T,
                                                  const unsigned short* __restrict__ frags) {
  __shared__ unsigned short sB[64 * 64];   // [c][hw]  8 KB
  __shared__ unsigned short sO[64 * 72];   // [o][hw+pad] 9 KB
  const int t = threadIdx.x;
  const int b = blockIdx.x >> 8;
  const int hw0 = (blockIdx.x & 255) << 6;
  const size_t bbase = (size_t)b << 20;    // b * 64 * 16384

  // stage f2 tile [64c][64hw] as bf16
  {
    const int c = t >> 2, m = t & 3;
    if (IN_BF16) {
      const unsigned short* src = (const unsigned short*)f2 + bbase + (size_t)c * 16384 + hw0 + m * 16;
      uint4 q0 = *(const uint4*)(src);
      uint4 q1 = *(const uint4*)(src + 8);
      *(uint4*)&sB[c * 64 + m * 16] = q0;
      *(uint4*)&sB[c * 64 + m * 16 + 8] = q1;
    } else {
      const float* src = (const float*)f2 + bbase + (size_t)c * 16384 + hw0 + m * 16;
      union { unsigned short u[16]; uint4 q[2]; } pk;
      #pragma unroll
      for (int g = 0; g < 4; ++g) {
        const float4 f = *(const float4*)(src + 4 * g);
        pk.u[4*g+0]=f2bf(f.x); pk.u[4*g+1]=f2bf(f.y); pk.u[4*g+2]=f2bf(f.z); pk.u[4*g+3]=f2bf(f.w);
      }
      *(uint4*)&sB[c * 64 + m * 16] = pk.q[0];
      *(uint4*)&sB[c * 64 + m * 16 + 8] = pk.q[1];
    }
  }

  const int lane = t & 63, wv = t >> 6;

  // A fragments (all 2 pods x 4 o-tiles x 2 k-chunks), 16B each per lane, L2-hot
  short8 afr[2][4][2];
  #pragma unroll
  for (int p = 0; p < 2; ++p)
    #pragma unroll
    for (int ot = 0; ot < 4; ++ot)
      #pragma unroll
      for (int kc = 0; kc < 2; ++kc)
        afr[p][ot][kc] = *(const short8*)(frags + ((((p << 2) | ot) << 1 | kc) << 9) + lane * 8);

  __syncthreads();

  // B fragments from LDS (k = kc*32 + 8*(lane>>4) + i, col = hw0 + wv*16 + (lane&15))
  short8 bfr[2];
  #pragma unroll
  for (int kc = 0; kc < 2; ++kc) {
    short8 bv;
    #pragma unroll
    for (int i = 0; i < 8; ++i)
      bv[i] = (short)sB[(kc * 32 + 8 * (lane >> 4) + i) * 64 + wv * 16 + (lane & 15)];
    bfr[kc] = bv;
  }

  const int hwl = hw0 + wv * 16 + (lane & 15);
  float facc[4][4];
  #pragma unroll
  for (int ot = 0; ot < 4; ++ot)
    #pragma unroll
    for (int i = 0; i < 4; ++i) facc[ot][i] = 0.f;

  #pragma unroll
  for (int p = 0; p < 2; ++p) {
    f32x4 acc[4];
    #pragma unroll
    for (int ot = 0; ot < 4; ++ot) acc[ot] = (f32x4){0.f, 0.f, 0.f, 0.f};
    #pragma unroll
    for (int kc = 0; kc < 2; ++kc)
      #pragma unroll
      for (int ot = 0; ot < 4; ++ot)
        acc[ot] = __builtin_amdgcn_mfma_f32_16x16x32_bf16(afr[p][ot][kc], bfr[kc], acc[ot], 0, 0, 0);
    const float vv = v[p * 16384 + hwl];
    const float tv = T[p * 16384 + hwl];
    #pragma unroll
    for (int ot = 0; ot < 4; ++ot)
      #pragma unroll
      for (int i = 0; i < 4; ++i) {
        const float fv = acc[ot][i] * vv;
        const float m = fabsf(fv) - tv;        // T >= 0 so relu(T)=T
        facc[ot][i] += (m > 0.f) ? copysignf(m, fv) : 0.f;
      }
  }

  // acc -> LDS (bf16), then coalesced global writes
  #pragma unroll
  for (int ot = 0; ot < 4; ++ot)
    #pragma unroll
    for (int i = 0; i < 4; ++i) {
      const int o = ot * 16 + 4 * (lane >> 4) + i;
      sO[o * 72 + wv * 16 + (lane & 15)] = f2bf(facc[ot][i]);
    }
  __syncthreads();

  #pragma unroll
  for (int iter = 0; iter < 2; ++iter) {
    const int e = iter * 2048 + t * 8;
    const int o = e >> 6, col = e & 63;
    const uint4 q = *(const uint4*)&sO[o * 72 + col];
    if (OUT_BF16) {
      *(uint4*)((unsigned short*)f6 + bbase + (size_t)o * 16384 + hw0 + col) = q;
    } else {
      union { unsigned short u[8]; uint4 q; } pk; pk.q = q;
      float* dst = (float*)f6 + bbase + (size_t)o * 16384 + hw0 + col;
      float4 f0 = {bf2f(pk.u[0]), bf2f(pk.u[1]), bf2f(pk.u[2]), bf2f(pk.u[3])};
      float4 f1 = {bf2f(pk.u[4]), bf2f(pk.u[5]), bf2f(pk.u[6]), bf2f(pk.u[7])};
      *(float4*)dst = f0;
      *(float4*)(dst + 4) = f1;
    }
  }
}

extern "C" void kernel_launch(void* const* d_in, const int* in_sizes, int n_in,
                              void* d_out, int out_size, void* d_ws, size_t ws_size,
                              hipStream_t stream) {
  const float* x = (const float*)d_in[0];
  const float* v = (const float*)d_in[1];
  const float* T = (const float*)d_in[2];
  const float* w = (const float*)d_in[3];
  float* out = (float*)d_out;

  unsigned short* frags = (unsigned short*)d_ws;               // 16 KB
  const size_t BF16_PLANE_BYTES = (size_t)33554432 * 2;        // 67.1 MB each
  const bool bigws = ws_size >= (size_t)16384 + 2 * BF16_PLANE_BYTES;

  prep_frags_kernel<<<32, 256, 0, stream>>>(w, frags);

  if (bigws) {
    unsigned short* f2b = (unsigned short*)((char*)d_ws + 16384);
    unsigned short* f6b = (unsigned short*)((char*)d_ws + 16384 + BF16_PLANE_BYTES);
    fwht2d_fwd_kernel<true><<<2048, 512, 0, stream>>>(x, f2b);
    mix_kernel<true, true><<<8192, 256, 0, stream>>>(f2b, f6b, v, T, frags);
    fwht2d_inv_kernel<true><<<2048, 512, 0, stream>>>(f6b, x, out);
  } else {
    fwht2d_fwd_kernel<false><<<2048, 512, 0, stream>>>(x, out);
    mix_kernel<false, false><<<8192, 256, 0, stream>>>(out, out, v, T, frags);
    fwht2d_inv_kernel<false><<<2048, 512, 0, stream>>>(out, x, out);
  }
}